// Round 12
// baseline (311.585 us; speedup 1.0000x reference)
//
#include <hip/hip_runtime.h>
#include <hip/hip_fp16.h>

#define N_NODES  100000
#define N_EDGES  1600000
#define N_GRAPHS 64

#define BINSH  8
#define NBIN   392          // bins of 256 nodes (last ones empty-guarded)
#define BINCAP 5120         // Poisson(4081) max ~4.4K; safe headroom
#define EPB    4096         // edges per block in k_binA (1024 threads x 4)

typedef _Float16 half8 __attribute__((ext_vector_type(8)));
typedef float float4v __attribute__((ext_vector_type(4)));

__device__ __forceinline__ float lrelu(float v) { return v > 0.f ? v : 0.2f * v; }
__device__ __forceinline__ float elu_f(float v) { return v > 0.f ? v : __expf(v) - 1.f; }

// ---- Pass A: coarse-bin edges (dst>>8) into per-bin regions, coalesced runs.
// binned entries packed: (dst_local << 17) | src.
__global__ __launch_bounds__(1024) void k_binA(
    const int* __restrict__ src, const int* __restrict__ dst,
    const int* __restrict__ batch, int* __restrict__ gbin_cursor,
    int* __restrict__ cnt, int* __restrict__ binned) {
    __shared__ int hist[NBIN], lexcl[NBIN], runbase[NBIN], lcur[NBIN];
    __shared__ int wpart[16];
    __shared__ int gh[N_GRAPHS];
    __shared__ int2 stage[EPB];   // {packed, bin}  32 KB
    int t = threadIdx.x;
    int e0 = blockIdx.x * EPB;
    for (int b = t; b < NBIN; b += 1024) hist[b] = 0;
    if (t < N_GRAPHS) gh[t] = 0;
    __syncthreads();
    int nid = blockIdx.x * 1024 + t;   // 391*1024 >= N_NODES
    if (nid < N_NODES) atomicAdd(&gh[batch[nid]], 1);
    int e = 4 * t;
    int4 dv = make_int4(0, 0, 0, 0), sv = make_int4(0, 0, 0, 0);
    bool full = (e0 + e + 3 < N_EDGES);
    if (full) {
        dv = *(const int4*)(dst + e0 + e);
        sv = *(const int4*)(src + e0 + e);
        atomicAdd(&hist[dv.x >> BINSH], 1);
        atomicAdd(&hist[dv.y >> BINSH], 1);
        atomicAdd(&hist[dv.z >> BINSH], 1);
        atomicAdd(&hist[dv.w >> BINSH], 1);
    } else {
        for (int k = 0; k < 4; ++k)
            if (e0 + e + k < N_EDGES) atomicAdd(&hist[dst[e0 + e + k] >> BINSH], 1);
    }
    __syncthreads();
    int v = (t < NBIN) ? hist[t] : 0;
    int x = v;
#pragma unroll
    for (int d = 1; d < 64; d <<= 1) {
        int y = __shfl_up(x, d, 64);
        if ((t & 63) >= d) x += y;
    }
    if ((t & 63) == 63) wpart[t >> 6] = x;
    __syncthreads();
    if (t == 0) {
        int a = 0;
        for (int w = 0; w < 16; ++w) { int q = wpart[w]; wpart[w] = a; a += q; }
    }
    __syncthreads();
    int excl = x - v + wpart[t >> 6];
    if (t < NBIN) { lexcl[t] = excl; lcur[t] = excl; }
    __syncthreads();
    if (t < NBIN && v > 0) runbase[t] = atomicAdd(&gbin_cursor[t], v);
    if (t < N_GRAPHS && gh[t]) atomicAdd(&cnt[t], gh[t]);
    __syncthreads();
    if (full) {
        int p, b_;
        b_ = dv.x >> BINSH; p = atomicAdd(&lcur[b_], 1);
        stage[p] = make_int2(((dv.x & 255) << 17) | sv.x, b_);
        b_ = dv.y >> BINSH; p = atomicAdd(&lcur[b_], 1);
        stage[p] = make_int2(((dv.y & 255) << 17) | sv.y, b_);
        b_ = dv.z >> BINSH; p = atomicAdd(&lcur[b_], 1);
        stage[p] = make_int2(((dv.z & 255) << 17) | sv.z, b_);
        b_ = dv.w >> BINSH; p = atomicAdd(&lcur[b_], 1);
        stage[p] = make_int2(((dv.w & 255) << 17) | sv.w, b_);
    } else {
        for (int k = 0; k < 4; ++k) {
            if (e0 + e + k < N_EDGES) {
                int d = dst[e0 + e + k];
                int b_ = d >> BINSH;
                int p = atomicAdd(&lcur[b_], 1);
                stage[p] = make_int2(((d & 255) << 17) | src[e0 + e + k], b_);
            }
        }
    }
    __syncthreads();
    int m = N_EDGES - e0;
    if (m > EPB) m = EPB;
    for (int i = 4 * t; i < 4 * t + 4 && i < m; ++i) {
        int2 pr = stage[i];
        int b_ = pr.y;
        binned[(size_t)b_ * BINCAP + runbase[b_] + (i - lexcl[b_])] = pr.x;
    }
}

// ---- MEGA pass B (R15-proven, monolithic; R21 split regressed ~15us):
// counting sort -> off/csr, then IN-BLOCK: layer-1 (shuffle-reduce),
// exact-fp32 logits, MFMA h2 GEMM.
__global__ __launch_bounds__(1024) void k_megaB(
    const int* __restrict__ binned, const int* __restrict__ gbin_cursor,
    int* __restrict__ off, int* __restrict__ csr,
    const float* __restrict__ x, const float* __restrict__ W1,
    const float* __restrict__ as1, const float* __restrict__ ad1,
    const float* __restrict__ b1, const float* __restrict__ W2,
    const float* __restrict__ as2, const float* __restrict__ ad2,
    __half2* __restrict__ h2p, float2* __restrict__ ap, float2* __restrict__ dp) {
    __shared__ int hist[256], lstart[256];
    __shared__ int wpart[4];
    __shared__ int s_ebase;
    __shared__ float s1l[256 * 8];
    __shared__ float smWs[512], smWd[512];
    __shared__ float smW1[64], smB1[64];
    __shared__ float ws8s[8], wd8s[8];
    __shared__ _Float16 smWT[128 * 72];
    __shared__ _Float16 smA[256 * 72];
    int b = blockIdx.x, t = threadIdx.x;
    int count = gbin_cursor[b];
    int node0 = b << BINSH;
    const int* my = binned + (size_t)b * BINCAP;

    if (t == 0) s_ebase = 0;
    if (t < 256) hist[t] = 0;
    for (int idx = t; idx < 8192; idx += 1024) {
        int c = idx >> 6, k = idx & 63;
        smWT[c * 72 + k] = (_Float16)W2[k * 128 + c];
    }
    {
        int tt = t & 511;
        int k = tt >> 3, h = tt & 7;
        const float* att = (t < 512) ? as2 : ad2;
        float acc = 0.f;
        for (int c = 0; c < 16; ++c)
            acc += W2[k * 128 + h * 16 + c] * att[h * 16 + c];
        if (t < 512) smWs[k * 8 + h] = acc; else smWd[k * 8 + h] = acc;
    }
    if (t < 64) { smW1[t] = W1[t]; smB1[t] = b1[t]; }
    if (t >= 64 && t < 72) {
        int h = t - 64;
        float s = 0.f, d = 0.f;
        for (int c = 0; c < 8; ++c) {
            float w = W1[h * 8 + c];
            s += w * as1[h * 8 + c];
            d += w * ad1[h * 8 + c];
        }
        ws8s[h] = s;
        wd8s[h] = d;
    }
    __syncthreads();

    if (t < b) atomicAdd(&s_ebase, gbin_cursor[t]);
    for (int i = t; i < count; i += 1024) atomicAdd(&hist[my[i] >> 17], 1);
    __syncthreads();

    int v = (t < 256) ? hist[t] : 0;
    int xx = v;
#pragma unroll
    for (int d = 1; d < 64; d <<= 1) {
        int y = __shfl_up(xx, d, 64);
        if ((t & 63) >= d) xx += y;
    }
    if (t < 256 && (t & 63) == 63) wpart[t >> 6] = xx;
    __syncthreads();
    if (t == 0) {
        int a = 0;
        for (int w = 0; w < 4; ++w) { int q = wpart[w]; wpart[w] = a; a += q; }
    }
    __syncthreads();
    int ebase = s_ebase;
    int excl = xx - v + ((t < 256) ? wpart[t >> 6] : 0);
    if (t < 256) {
        int n = node0 + t;
        if (n < N_NODES) off[n] = ebase + excl;
        lstart[t] = excl;
        hist[t] = excl;    // cursor
    }
    if (b == 0 && t == 0) off[N_NODES] = N_EDGES;
    __syncthreads();

    for (int i = t; i < count; i += 1024) {
        int pr = my[i];
        int p = atomicAdd(&hist[pr >> 17], 1);
        csr[ebase + p] = pr & 0x1FFFF;
    }
    __syncthreads();

    // layer 1: 4 lanes/node shuffle-reduce
    {
        int nl = t >> 2, c = t & 3;
        int n = node0 + nl;
        float ws[8], wd[8];
#pragma unroll
        for (int h = 0; h < 8; ++h) { ws[h] = ws8s[h]; wd[h] = wd8s[h]; }
        float xn = (n < N_NODES) ? x[n] : 0.f;
        float num[8], den[8];
#pragma unroll
        for (int h = 0; h < 8; ++h) { num[h] = 0.f; den[h] = 0.f; }
        if (c == 0 && n < N_NODES) {
#pragma unroll
            for (int h = 0; h < 8; ++h) {
                float w = __expf(lrelu(xn * ws[h] + xn * wd[h]));
                den[h] = w;
                num[h] = w * xn;
            }
        }
        int st = lstart[nl], en = hist[nl];
        for (int j = st + c; j < en; j += 4) {
            int s = csr[ebase + j];
            float xs = x[s];
#pragma unroll
            for (int h = 0; h < 8; ++h) {
                float w = __expf(lrelu(xs * ws[h] + xn * wd[h]));
                den[h] += w;
                num[h] += w * xs;
            }
        }
#pragma unroll
        for (int d = 1; d < 4; d <<= 1) {
#pragma unroll
            for (int h = 0; h < 8; ++h) {
                num[h] += __shfl_xor(num[h], d, 64);
                den[h] += __shfl_xor(den[h], d, 64);
            }
        }
        if (c == 0) {
#pragma unroll
            for (int h = 0; h < 8; ++h)
                s1l[nl * 8 + h] = (n < N_NODES) ? num[h] / den[h] : 0.f;
        }
    }
    __syncthreads();

    // exact-fp32 logits + smA fill
    {
        int nl = t >> 2, j = t & 3;
        int n = node0 + nl;
        if (n < N_NODES) {
            float pSA = 0.f, pSB = 0.f, pDA = 0.f, pDB = 0.f;
#pragma unroll 8
            for (int k = 0; k < 64; ++k) {
                float h1a = elu_f(s1l[nl * 8 + (k >> 3)] * smW1[k] + smB1[k]);
                pSA += h1a * smWs[k * 8 + j];
                pSB += h1a * smWs[k * 8 + j + 4];
                pDA += h1a * smWd[k * 8 + j];
                pDB += h1a * smWd[k * 8 + j + 4];
            }
            ap[n * 4 + j] = make_float2(pSA, pSB);
            dp[n * 4 + j] = make_float2(pDA, pDB);
        }
    }
    for (int i = t; i < 256 * 64; i += 1024) {
        int m = i >> 6, k = i & 63;
        smA[m * 72 + k] = (_Float16)elu_f(s1l[m * 8 + (k >> 3)] * smW1[k] + smB1[k]);
    }
    __syncthreads();

    // MFMA h2 GEMM, 16 waves x 16 nodes
    {
        int wave = t >> 6, lane = t & 63;
        int quad = lane >> 4, m15 = lane & 15;
        half8 a0 = *reinterpret_cast<const half8*>(&smA[(wave * 16 + m15) * 72 + quad * 8]);
        half8 a1 = *reinterpret_cast<const half8*>(&smA[(wave * 16 + m15) * 72 + 32 + quad * 8]);
        float4v acc[8];
#pragma unroll
        for (int tl = 0; tl < 8; ++tl) {
            half8 b0 = *reinterpret_cast<const half8*>(&smWT[(tl * 16 + m15) * 72 + quad * 8]);
            half8 b1v = *reinterpret_cast<const half8*>(&smWT[(tl * 16 + m15) * 72 + 32 + quad * 8]);
            float4v c = {0.f, 0.f, 0.f, 0.f};
            c = __builtin_amdgcn_mfma_f32_16x16x32_f16(a0, b0, c, 0, 0, 0);
            c = __builtin_amdgcn_mfma_f32_16x16x32_f16(a1, b1v, c, 0, 0, 0);
            acc[tl] = c;
        }
#pragma unroll
        for (int tl = 0; tl < 4; ++tl) {
#pragma unroll
            for (int reg = 0; reg < 4; ++reg) {
                int n = node0 + wave * 16 + quad * 4 + reg;
                if (n < N_NODES)
                    h2p[n * 64 + tl * 16 + m15] =
                        __floats2half2_rn(acc[tl][reg], acc[tl + 4][reg]);
            }
        }
    }
}

// ---- Layer 2 aggregation, R25: first-16-edges UNCONDITIONAL burst.
// R23/R24 lesson: gbuf under ANY condition the compiler can't prove
// wave-uniform gets exec-mask-predicated -> aggregate spills to scratch
// (R24: WRITE_SIZE 1.5->51 MB, VGPR stuck 32). Fix: groups 0,1 run with
// NO guard at all -- padding makes them safe (sl lanes >= c0 hold SELF
// node; their weights are 0 via select; wasted loads are L1-hits on the
// already-read self row). The 16-load burst is top-level straight-line
// code: nothing to predicate, nothing to spill. Groups 2..7 keep R22's
// exact guarded form (proven 98us). P(deg<=16)~54% -> most nodes finish
// in the burst.
__global__ __launch_bounds__(256, 8) void k_layer2(
    const __half2* __restrict__ h2p, const float2* __restrict__ ap,
    const float2* __restrict__ dp, const int* __restrict__ off,
    const int* __restrict__ csr, const int* __restrict__ batch,
    float* __restrict__ pool) {
    __shared__ float smv[4][16];
    __shared__ int smg[4];
    const float* apf = (const float*)ap;   // flat: node*8 + 2*(h&3) + (h>>2)
    const float* dpf = (const float*)dp;
    int t = threadIdx.x;
    int wid = t >> 6, l = t & 63;
    int n = blockIdx.x * 4 + wid;  // grid exact: 25000*4 == N_NODES
    int hA = l >> 4;               // head of x component; y component = hA+4
    int hh = l & 7;
    int j8 = l >> 3;
    int fidx = 2 * (hh & 3) + (hh >> 2);
    float dn = dpf[n * 8 + fidx];

    // self-loop seed
    float2 ad = dp[n * 4 + hA];
    float2 an = ap[n * 4 + hA];
    float wA = __expf(lrelu(an.x + ad.x));
    float wB = __expf(lrelu(an.y + ad.y));
    float2 hn = __half22float2(h2p[(size_t)n * 64 + l]);
    float accA = wA * hn.x, accB = wB * hn.y;
    float wsum = 0.f;

    int b = off[n];
    int deg = off[n + 1] - b;
    int c0 = deg < 64 ? deg : 64;
    int sl = (l < c0) ? csr[b + l] : n;   // pad with self (valid address)

    float w_reg[8];
#pragma unroll
    for (int k = 0; k < 8; ++k) w_reg[k] = 0.f;

    // pass 1, groups 0-1: UNCONDITIONAL (masked by select).
    {
        int sg0 = __shfl(sl, j8, 64);
        int sg1 = __shfl(sl, 8 + j8, 64);
        float w0 = __expf(lrelu(apf[sg0 * 8 + fidx] + dn));
        float w1 = __expf(lrelu(apf[sg1 * 8 + fidx] + dn));
        w_reg[0] = (j8 < c0) ? w0 : 0.f;
        w_reg[1] = (8 + j8 < c0) ? w1 : 0.f;
        wsum += w_reg[0] + w_reg[1];
    }
    // pass 1, groups 2-7: R22 guarded form.
#pragma unroll
    for (int k = 2; k < 8; ++k) {
        if (8 * k < c0) {
            int sg = __shfl(sl, 8 * k + j8, 64);
            float w = __expf(lrelu(apf[sg * 8 + fidx] + dn));
            w = (8 * k + j8 < c0) ? w : 0.f;
            w_reg[k] = w;
            wsum += w;
        }
    }

    // pass 2, groups 0-1: unconditional straight-line 16-load burst.
    {
        __half2 gbuf[16];
#pragma unroll
        for (int e = 0; e < 16; ++e) {
            int s = __builtin_amdgcn_readlane(sl, e);
            gbuf[e] = h2p[(size_t)s * 64 + l];
        }
#pragma unroll
        for (int e = 0; e < 8; ++e) {
            float wa = __shfl(w_reg[0], e * 8 + hA, 64);
            float wb = __shfl(w_reg[0], e * 8 + hA + 4, 64);
            float2 gf = __half22float2(gbuf[e]);
            accA = fmaf(wa, gf.x, accA);
            accB = fmaf(wb, gf.y, accB);
        }
#pragma unroll
        for (int e = 0; e < 8; ++e) {
            float wa = __shfl(w_reg[1], e * 8 + hA, 64);
            float wb = __shfl(w_reg[1], e * 8 + hA + 4, 64);
            float2 gf = __half22float2(gbuf[8 + e]);
            accA = fmaf(wa, gf.x, accA);
            accB = fmaf(wb, gf.y, accB);
        }
    }
    // pass 2, groups 2-7: R22 guarded single-group bodies.
#pragma unroll
    for (int k = 2; k < 8; ++k) {
        if (8 * k < c0) {
#pragma unroll
            for (int e = 0; e < 8; ++e) {
                int s = __builtin_amdgcn_readlane(sl, 8 * k + e);
                float wa = __shfl(w_reg[k], e * 8 + hA, 64);
                float wb = __shfl(w_reg[k], e * 8 + hA + 4, 64);
                float2 gf = __half22float2(h2p[(size_t)s * 64 + l]);
                accA = fmaf(wa, gf.x, accA);
                accB = fmaf(wb, gf.y, accB);
            }
        }
    }

    // deg>64 fallback (P~0 for Poisson(16)): R0's 2-hop loop, verbatim.
    for (int base = 64; base < deg; base += 64) {
        int rem = deg - base;
        if (rem > 64) rem = 64;
        int sl2 = (l < rem) ? csr[b + base + l] : 0;
        int g = 0;
        for (; g + 8 <= rem; g += 8) {
            int sg = __shfl(sl2, g + j8, 64);
            float w = __expf(lrelu(apf[sg * 8 + fidx] + dn));
            wsum += w;
#pragma unroll
            for (int j2 = 0; j2 < 8; ++j2) {
                int s = __builtin_amdgcn_readlane(sl2, g + j2);
                float wa = __shfl(w, j2 * 8 + hA, 64);
                float wb = __shfl(w, j2 * 8 + hA + 4, 64);
                float2 gg = __half22float2(h2p[(size_t)s * 64 + l]);
                accA = fmaf(wa, gg.x, accA);
                accB = fmaf(wb, gg.y, accB);
            }
        }
        if (g < rem) {
            int cnt2 = rem - g;
            int jj = (j8 < cnt2) ? j8 : 0;
            int sg = __shfl(sl2, g + jj, 64);
            float w = (j8 < cnt2) ? __expf(lrelu(apf[sg * 8 + fidx] + dn)) : 0.f;
            wsum += w;
            for (int j2 = 0; j2 < cnt2; ++j2) {
                int s = __builtin_amdgcn_readlane(sl2, g + j2);
                float wa = __shfl(w, j2 * 8 + hA, 64);
                float wb = __shfl(w, j2 * 8 + hA + 4, 64);
                float2 gg = __half22float2(h2p[(size_t)s * 64 + l]);
                accA = fmaf(wa, gg.x, accA);
                accB = fmaf(wb, gg.y, accB);
            }
        }
    }

    // edge-weight totals: after xor 8/16/32, lane m holds head m&7 total
    wsum += __shfl_xor(wsum, 8, 64);
    wsum += __shfl_xor(wsum, 16, 64);
    wsum += __shfl_xor(wsum, 32, 64);
    float denA = wA + __shfl(wsum, hA, 64);
    float denB = wB + __shfl(wsum, hA + 4, 64);

    // channel c=l&15: lanes {l, l^16, l^32, l^48} hold heads {0..3}x{+0,+4}
    float v = accA / denA + accB / denB;
    v += __shfl_xor(v, 16, 64);
    v += __shfl_xor(v, 32, 64);
    v *= 0.125f;
    if (l < 16) smv[wid][l] = v;
    if (l == 0) smg[wid] = batch[n];
    __syncthreads();
    if (t < 64) {
        int w = t >> 4, c = t & 15;
        int g = smg[w];
        bool leader = true;
        for (int w2 = 0; w2 < w; ++w2)
            if (smg[w2] == g) { leader = false; break; }
        if (leader) {
            float s = smv[w][c];
            for (int w2 = w + 1; w2 < 4; ++w2)
                if (smg[w2] == g) s += smv[w2][c];
            atomicAdd(&pool[g * 16 + c], s);
        }
    }
}

// ---- final: pooled mean (+b2) @ Wfc + bfc -> [64,4]
__global__ void k_final(const float* __restrict__ pool, const int* __restrict__ cnt,
                        const float* __restrict__ b2, const float* __restrict__ Wfc,
                        const float* __restrict__ bfc, float* __restrict__ out) {
    int t = threadIdx.x;
    int g = t >> 2, k = t & 3;
    float c = (float)(cnt[g] > 0 ? cnt[g] : 1);
    float acc = bfc[k];
#pragma unroll
    for (int ci = 0; ci < 16; ++ci)
        acc += (pool[g * 16 + ci] / c + b2[ci]) * Wfc[ci * 4 + k];
    out[g * 4 + k] = acc;
}

extern "C" void kernel_launch(void* const* d_in, const int* in_sizes, int n_in,
                              void* d_out, int out_size, void* d_ws, size_t ws_size,
                              hipStream_t stream) {
    const float* x   = (const float*)d_in[0];
    const float* W1  = (const float*)d_in[1];
    const float* as1 = (const float*)d_in[2];
    const float* ad1 = (const float*)d_in[3];
    const float* b1  = (const float*)d_in[4];
    const float* W2  = (const float*)d_in[5];
    const float* as2 = (const float*)d_in[6];
    const float* ad2 = (const float*)d_in[7];
    const float* b2  = (const float*)d_in[8];
    const float* Wfc = (const float*)d_in[9];
    const float* bfc = (const float*)d_in[10];
    const int* ei    = (const int*)d_in[11];
    const int* batch = (const int*)d_in[12];
    const int* srcv  = ei;             // edge_index[0]
    const int* dstv  = ei + N_EDGES;   // edge_index[1]

    char* ws = (char*)d_ws;
    size_t o = 0;
    auto alloc = [&](size_t bytes) {
        void* p = ws + o;
        o += (bytes + 255) & ~(size_t)255;
        return p;
    };
    // zero-region first (one memset): cnt, pool, gbin_cursor
    int*    cnt     = (int*)alloc(64 * 4);
    float*  pool    = (float*)alloc(64 * 16 * 4);
    int*    gbin    = (int*)alloc(NBIN * 4);
    size_t  zbytes  = o;
    int*    off     = (int*)alloc((size_t)(N_NODES + 1) * 4);
    int*    csr     = (int*)alloc((size_t)N_EDGES * 4);
    float2* ap      = (float2*)alloc((size_t)N_NODES * 4 * 8);
    float2* dp      = (float2*)alloc((size_t)N_NODES * 4 * 8);
    int*    binned  = (int*)alloc((size_t)NBIN * BINCAP * 4);    // 8.0 MB packed
    __half2* h2p    = (__half2*)alloc((size_t)N_NODES * 64 * 4); // 25.6 MB

    hipMemsetAsync(d_ws, 0, zbytes, stream);

    int nbA = (N_EDGES + EPB - 1) / EPB;   // 391

    k_binA<<<nbA, 1024, 0, stream>>>(srcv, dstv, batch, gbin, cnt, binned);
    k_megaB<<<NBIN, 1024, 0, stream>>>(binned, gbin, off, csr,
                                       x, W1, as1, ad1, b1, W2, as2, ad2,
                                       h2p, ap, dp);
    k_layer2<<<N_NODES / 4, 256, 0, stream>>>(h2p, ap, dp, off, csr, batch, pool);
    k_final<<<1, 256, 0, stream>>>(pool, cnt, b2, Wfc, bfc, (float*)d_out);
}

// Round 13
// 282.027 us; speedup vs baseline: 1.1048x; 1.1048x over previous
//
#include <hip/hip_runtime.h>
#include <hip/hip_fp16.h>

#define N_NODES  100000
#define N_EDGES  1600000
#define N_GRAPHS 64

#define BINSH  8
#define NBIN   392          // bins of 256 nodes (last ones empty-guarded)
#define BINCAP 5120         // Poisson(4081) max ~4.4K; safe headroom
#define EPB    4096         // edges per block in k_binA (1024 threads x 4)

typedef _Float16 half8 __attribute__((ext_vector_type(8)));
typedef float float4v __attribute__((ext_vector_type(4)));

__device__ __forceinline__ float lrelu(float v) { return v > 0.f ? v : 0.2f * v; }
__device__ __forceinline__ float elu_f(float v) { return v > 0.f ? v : __expf(v) - 1.f; }

// ---- Pass A: coarse-bin edges (dst>>8) into per-bin regions, coalesced runs.
// binned entries packed: (dst_local << 17) | src.
__global__ __launch_bounds__(1024) void k_binA(
    const int* __restrict__ src, const int* __restrict__ dst,
    const int* __restrict__ batch, int* __restrict__ gbin_cursor,
    int* __restrict__ cnt, int* __restrict__ binned) {
    __shared__ int hist[NBIN], lexcl[NBIN], runbase[NBIN], lcur[NBIN];
    __shared__ int wpart[16];
    __shared__ int gh[N_GRAPHS];
    __shared__ int2 stage[EPB];   // {packed, bin}  32 KB
    int t = threadIdx.x;
    int e0 = blockIdx.x * EPB;
    for (int b = t; b < NBIN; b += 1024) hist[b] = 0;
    if (t < N_GRAPHS) gh[t] = 0;
    __syncthreads();
    int nid = blockIdx.x * 1024 + t;   // 391*1024 >= N_NODES
    if (nid < N_NODES) atomicAdd(&gh[batch[nid]], 1);
    int e = 4 * t;
    int4 dv = make_int4(0, 0, 0, 0), sv = make_int4(0, 0, 0, 0);
    bool full = (e0 + e + 3 < N_EDGES);
    if (full) {
        dv = *(const int4*)(dst + e0 + e);
        sv = *(const int4*)(src + e0 + e);
        atomicAdd(&hist[dv.x >> BINSH], 1);
        atomicAdd(&hist[dv.y >> BINSH], 1);
        atomicAdd(&hist[dv.z >> BINSH], 1);
        atomicAdd(&hist[dv.w >> BINSH], 1);
    } else {
        for (int k = 0; k < 4; ++k)
            if (e0 + e + k < N_EDGES) atomicAdd(&hist[dst[e0 + e + k] >> BINSH], 1);
    }
    __syncthreads();
    int v = (t < NBIN) ? hist[t] : 0;
    int x = v;
#pragma unroll
    for (int d = 1; d < 64; d <<= 1) {
        int y = __shfl_up(x, d, 64);
        if ((t & 63) >= d) x += y;
    }
    if ((t & 63) == 63) wpart[t >> 6] = x;
    __syncthreads();
    if (t == 0) {
        int a = 0;
        for (int w = 0; w < 16; ++w) { int q = wpart[w]; wpart[w] = a; a += q; }
    }
    __syncthreads();
    int excl = x - v + wpart[t >> 6];
    if (t < NBIN) { lexcl[t] = excl; lcur[t] = excl; }
    __syncthreads();
    if (t < NBIN && v > 0) runbase[t] = atomicAdd(&gbin_cursor[t], v);
    if (t < N_GRAPHS && gh[t]) atomicAdd(&cnt[t], gh[t]);
    __syncthreads();
    if (full) {
        int p, b_;
        b_ = dv.x >> BINSH; p = atomicAdd(&lcur[b_], 1);
        stage[p] = make_int2(((dv.x & 255) << 17) | sv.x, b_);
        b_ = dv.y >> BINSH; p = atomicAdd(&lcur[b_], 1);
        stage[p] = make_int2(((dv.y & 255) << 17) | sv.y, b_);
        b_ = dv.z >> BINSH; p = atomicAdd(&lcur[b_], 1);
        stage[p] = make_int2(((dv.z & 255) << 17) | sv.z, b_);
        b_ = dv.w >> BINSH; p = atomicAdd(&lcur[b_], 1);
        stage[p] = make_int2(((dv.w & 255) << 17) | sv.w, b_);
    } else {
        for (int k = 0; k < 4; ++k) {
            if (e0 + e + k < N_EDGES) {
                int d = dst[e0 + e + k];
                int b_ = d >> BINSH;
                int p = atomicAdd(&lcur[b_], 1);
                stage[p] = make_int2(((d & 255) << 17) | src[e0 + e + k], b_);
            }
        }
    }
    __syncthreads();
    int m = N_EDGES - e0;
    if (m > EPB) m = EPB;
    for (int i = 4 * t; i < 4 * t + 4 && i < m; ++i) {
        int2 pr = stage[i];
        int b_ = pr.y;
        binned[(size_t)b_ * BINCAP + runbase[b_] + (i - lexcl[b_])] = pr.x;
    }
}

// ---- MEGA pass B (R15-proven, monolithic; R21 split regressed ~15us):
// counting sort -> off/csr, then IN-BLOCK: layer-1 (shuffle-reduce),
// exact-fp32 logits, MFMA h2 GEMM.
__global__ __launch_bounds__(1024) void k_megaB(
    const int* __restrict__ binned, const int* __restrict__ gbin_cursor,
    int* __restrict__ off, int* __restrict__ csr,
    const float* __restrict__ x, const float* __restrict__ W1,
    const float* __restrict__ as1, const float* __restrict__ ad1,
    const float* __restrict__ b1, const float* __restrict__ W2,
    const float* __restrict__ as2, const float* __restrict__ ad2,
    __half2* __restrict__ h2p, float2* __restrict__ ap, float2* __restrict__ dp) {
    __shared__ int hist[256], lstart[256];
    __shared__ int wpart[4];
    __shared__ int s_ebase;
    __shared__ float s1l[256 * 8];
    __shared__ float smWs[512], smWd[512];
    __shared__ float smW1[64], smB1[64];
    __shared__ float ws8s[8], wd8s[8];
    __shared__ _Float16 smWT[128 * 72];
    __shared__ _Float16 smA[256 * 72];
    int b = blockIdx.x, t = threadIdx.x;
    int count = gbin_cursor[b];
    int node0 = b << BINSH;
    const int* my = binned + (size_t)b * BINCAP;

    if (t == 0) s_ebase = 0;
    if (t < 256) hist[t] = 0;
    for (int idx = t; idx < 8192; idx += 1024) {
        int c = idx >> 6, k = idx & 63;
        smWT[c * 72 + k] = (_Float16)W2[k * 128 + c];
    }
    {
        int tt = t & 511;
        int k = tt >> 3, h = tt & 7;
        const float* att = (t < 512) ? as2 : ad2;
        float acc = 0.f;
        for (int c = 0; c < 16; ++c)
            acc += W2[k * 128 + h * 16 + c] * att[h * 16 + c];
        if (t < 512) smWs[k * 8 + h] = acc; else smWd[k * 8 + h] = acc;
    }
    if (t < 64) { smW1[t] = W1[t]; smB1[t] = b1[t]; }
    if (t >= 64 && t < 72) {
        int h = t - 64;
        float s = 0.f, d = 0.f;
        for (int c = 0; c < 8; ++c) {
            float w = W1[h * 8 + c];
            s += w * as1[h * 8 + c];
            d += w * ad1[h * 8 + c];
        }
        ws8s[h] = s;
        wd8s[h] = d;
    }
    __syncthreads();

    if (t < b) atomicAdd(&s_ebase, gbin_cursor[t]);
    for (int i = t; i < count; i += 1024) atomicAdd(&hist[my[i] >> 17], 1);
    __syncthreads();

    int v = (t < 256) ? hist[t] : 0;
    int xx = v;
#pragma unroll
    for (int d = 1; d < 64; d <<= 1) {
        int y = __shfl_up(xx, d, 64);
        if ((t & 63) >= d) xx += y;
    }
    if (t < 256 && (t & 63) == 63) wpart[t >> 6] = xx;
    __syncthreads();
    if (t == 0) {
        int a = 0;
        for (int w = 0; w < 4; ++w) { int q = wpart[w]; wpart[w] = a; a += q; }
    }
    __syncthreads();
    int ebase = s_ebase;
    int excl = xx - v + ((t < 256) ? wpart[t >> 6] : 0);
    if (t < 256) {
        int n = node0 + t;
        if (n < N_NODES) off[n] = ebase + excl;
        lstart[t] = excl;
        hist[t] = excl;    // cursor
    }
    if (b == 0 && t == 0) off[N_NODES] = N_EDGES;
    __syncthreads();

    for (int i = t; i < count; i += 1024) {
        int pr = my[i];
        int p = atomicAdd(&hist[pr >> 17], 1);
        csr[ebase + p] = pr & 0x1FFFF;
    }
    __syncthreads();

    // layer 1: 4 lanes/node shuffle-reduce
    {
        int nl = t >> 2, c = t & 3;
        int n = node0 + nl;
        float ws[8], wd[8];
#pragma unroll
        for (int h = 0; h < 8; ++h) { ws[h] = ws8s[h]; wd[h] = wd8s[h]; }
        float xn = (n < N_NODES) ? x[n] : 0.f;
        float num[8], den[8];
#pragma unroll
        for (int h = 0; h < 8; ++h) { num[h] = 0.f; den[h] = 0.f; }
        if (c == 0 && n < N_NODES) {
#pragma unroll
            for (int h = 0; h < 8; ++h) {
                float w = __expf(lrelu(xn * ws[h] + xn * wd[h]));
                den[h] = w;
                num[h] = w * xn;
            }
        }
        int st = lstart[nl], en = hist[nl];
        for (int j = st + c; j < en; j += 4) {
            int s = csr[ebase + j];
            float xs = x[s];
#pragma unroll
            for (int h = 0; h < 8; ++h) {
                float w = __expf(lrelu(xs * ws[h] + xn * wd[h]));
                den[h] += w;
                num[h] += w * xs;
            }
        }
#pragma unroll
        for (int d = 1; d < 4; d <<= 1) {
#pragma unroll
            for (int h = 0; h < 8; ++h) {
                num[h] += __shfl_xor(num[h], d, 64);
                den[h] += __shfl_xor(den[h], d, 64);
            }
        }
        if (c == 0) {
#pragma unroll
            for (int h = 0; h < 8; ++h)
                s1l[nl * 8 + h] = (n < N_NODES) ? num[h] / den[h] : 0.f;
        }
    }
    __syncthreads();

    // exact-fp32 logits + smA fill
    {
        int nl = t >> 2, j = t & 3;
        int n = node0 + nl;
        if (n < N_NODES) {
            float pSA = 0.f, pSB = 0.f, pDA = 0.f, pDB = 0.f;
#pragma unroll 8
            for (int k = 0; k < 64; ++k) {
                float h1a = elu_f(s1l[nl * 8 + (k >> 3)] * smW1[k] + smB1[k]);
                pSA += h1a * smWs[k * 8 + j];
                pSB += h1a * smWs[k * 8 + j + 4];
                pDA += h1a * smWd[k * 8 + j];
                pDB += h1a * smWd[k * 8 + j + 4];
            }
            ap[n * 4 + j] = make_float2(pSA, pSB);
            dp[n * 4 + j] = make_float2(pDA, pDB);
        }
    }
    for (int i = t; i < 256 * 64; i += 1024) {
        int m = i >> 6, k = i & 63;
        smA[m * 72 + k] = (_Float16)elu_f(s1l[m * 8 + (k >> 3)] * smW1[k] + smB1[k]);
    }
    __syncthreads();

    // MFMA h2 GEMM, 16 waves x 16 nodes
    {
        int wave = t >> 6, lane = t & 63;
        int quad = lane >> 4, m15 = lane & 15;
        half8 a0 = *reinterpret_cast<const half8*>(&smA[(wave * 16 + m15) * 72 + quad * 8]);
        half8 a1 = *reinterpret_cast<const half8*>(&smA[(wave * 16 + m15) * 72 + 32 + quad * 8]);
        float4v acc[8];
#pragma unroll
        for (int tl = 0; tl < 8; ++tl) {
            half8 b0 = *reinterpret_cast<const half8*>(&smWT[(tl * 16 + m15) * 72 + quad * 8]);
            half8 b1v = *reinterpret_cast<const half8*>(&smWT[(tl * 16 + m15) * 72 + 32 + quad * 8]);
            float4v c = {0.f, 0.f, 0.f, 0.f};
            c = __builtin_amdgcn_mfma_f32_16x16x32_f16(a0, b0, c, 0, 0, 0);
            c = __builtin_amdgcn_mfma_f32_16x16x32_f16(a1, b1v, c, 0, 0, 0);
            acc[tl] = c;
        }
#pragma unroll
        for (int tl = 0; tl < 4; ++tl) {
#pragma unroll
            for (int reg = 0; reg < 4; ++reg) {
                int n = node0 + wave * 16 + quad * 4 + reg;
                if (n < N_NODES)
                    h2p[n * 64 + tl * 16 + m15] =
                        __floats2half2_rn(acc[tl][reg], acc[tl + 4][reg]);
            }
        }
    }
}

// ---- Layer 2 aggregation, R26: R22 + 16 NAMED-SCALAR staged gathers.
// Spill forensics: R24 (guarded gbuf) and R25 (top-level gbuf) both sent
// the __half2[16] aggregate to scratch (WRITE_SIZE 1.5->51/277 MB, VGPR
// pegged 32) -- the compiler never SROA-promotes the aggregate. Final
// expression: 16 independent named `unsigned int` scalars (SSA values,
// nothing to promote), loaded unconditionally via a uint* view; padding
// (sl>=c0 -> self node) keeps addresses valid, w_reg==0 kills their
// contribution. Groups 2-7 and all else: R22 verbatim (proven 98us).
// Pre-registered: if this also fails -> revert R22, declare plateau.
__global__ __launch_bounds__(256, 8) void k_layer2(
    const __half2* __restrict__ h2p, const float2* __restrict__ ap,
    const float2* __restrict__ dp, const int* __restrict__ off,
    const int* __restrict__ csr, const int* __restrict__ batch,
    float* __restrict__ pool) {
    __shared__ float smv[4][16];
    __shared__ int smg[4];
    const float* apf = (const float*)ap;   // flat: node*8 + 2*(h&3) + (h>>2)
    const float* dpf = (const float*)dp;
    const unsigned int* h2u = (const unsigned int*)h2p;
    int t = threadIdx.x;
    int wid = t >> 6, l = t & 63;
    int n = blockIdx.x * 4 + wid;  // grid exact: 25000*4 == N_NODES
    int hA = l >> 4;               // head of x component; y component = hA+4
    int hh = l & 7;
    int j8 = l >> 3;
    int fidx = 2 * (hh & 3) + (hh >> 2);
    float dn = dpf[n * 8 + fidx];

    // self-loop seed
    float2 ad = dp[n * 4 + hA];
    float2 an = ap[n * 4 + hA];
    float wA = __expf(lrelu(an.x + ad.x));
    float wB = __expf(lrelu(an.y + ad.y));
    float2 hn = __half22float2(h2p[(size_t)n * 64 + l]);
    float accA = wA * hn.x, accB = wB * hn.y;
    float wsum = 0.f;

    int b = off[n];
    int deg = off[n + 1] - b;
    int c0 = deg < 64 ? deg : 64;
    int sl = (l < c0) ? csr[b + l] : n;   // pad with self (valid address)

    float w_reg[8];
#pragma unroll
    for (int k = 0; k < 8; ++k) w_reg[k] = 0.f;

    // pass 1, groups 0-1: UNCONDITIONAL (masked by select).
    {
        int sg0 = __shfl(sl, j8, 64);
        int sg1 = __shfl(sl, 8 + j8, 64);
        float w0 = __expf(lrelu(apf[sg0 * 8 + fidx] + dn));
        float w1 = __expf(lrelu(apf[sg1 * 8 + fidx] + dn));
        w_reg[0] = (j8 < c0) ? w0 : 0.f;
        w_reg[1] = (8 + j8 < c0) ? w1 : 0.f;
        wsum += w_reg[0] + w_reg[1];
    }
    // pass 1, groups 2-7: R22 guarded form.
#pragma unroll
    for (int k = 2; k < 8; ++k) {
        if (8 * k < c0) {
            int sg = __shfl(sl, 8 * k + j8, 64);
            float w = __expf(lrelu(apf[sg * 8 + fidx] + dn));
            w = (8 * k + j8 < c0) ? w : 0.f;
            w_reg[k] = w;
            wsum += w;
        }
    }

    // pass 2, groups 0-1: 16 unconditional NAMED-SCALAR staged gathers.
    {
        unsigned int g0, g1, g2, g3, g4, g5, g6, g7;
        unsigned int g8, g9, g10, g11, g12, g13, g14, g15;
        g0  = h2u[(size_t)__builtin_amdgcn_readlane(sl,  0) * 64 + l];
        g1  = h2u[(size_t)__builtin_amdgcn_readlane(sl,  1) * 64 + l];
        g2  = h2u[(size_t)__builtin_amdgcn_readlane(sl,  2) * 64 + l];
        g3  = h2u[(size_t)__builtin_amdgcn_readlane(sl,  3) * 64 + l];
        g4  = h2u[(size_t)__builtin_amdgcn_readlane(sl,  4) * 64 + l];
        g5  = h2u[(size_t)__builtin_amdgcn_readlane(sl,  5) * 64 + l];
        g6  = h2u[(size_t)__builtin_amdgcn_readlane(sl,  6) * 64 + l];
        g7  = h2u[(size_t)__builtin_amdgcn_readlane(sl,  7) * 64 + l];
        g8  = h2u[(size_t)__builtin_amdgcn_readlane(sl,  8) * 64 + l];
        g9  = h2u[(size_t)__builtin_amdgcn_readlane(sl,  9) * 64 + l];
        g10 = h2u[(size_t)__builtin_amdgcn_readlane(sl, 10) * 64 + l];
        g11 = h2u[(size_t)__builtin_amdgcn_readlane(sl, 11) * 64 + l];
        g12 = h2u[(size_t)__builtin_amdgcn_readlane(sl, 12) * 64 + l];
        g13 = h2u[(size_t)__builtin_amdgcn_readlane(sl, 13) * 64 + l];
        g14 = h2u[(size_t)__builtin_amdgcn_readlane(sl, 14) * 64 + l];
        g15 = h2u[(size_t)__builtin_amdgcn_readlane(sl, 15) * 64 + l];
#define ACC26(gv, wr, e) { \
        float wa = __shfl(wr, (e) * 8 + hA, 64); \
        float wb = __shfl(wr, (e) * 8 + hA + 4, 64); \
        __half2 hv = *reinterpret_cast<__half2*>(&gv); \
        float2 gf = __half22float2(hv); \
        accA = fmaf(wa, gf.x, accA); \
        accB = fmaf(wb, gf.y, accB); }
        ACC26(g0,  w_reg[0], 0) ACC26(g1,  w_reg[0], 1)
        ACC26(g2,  w_reg[0], 2) ACC26(g3,  w_reg[0], 3)
        ACC26(g4,  w_reg[0], 4) ACC26(g5,  w_reg[0], 5)
        ACC26(g6,  w_reg[0], 6) ACC26(g7,  w_reg[0], 7)
        ACC26(g8,  w_reg[1], 0) ACC26(g9,  w_reg[1], 1)
        ACC26(g10, w_reg[1], 2) ACC26(g11, w_reg[1], 3)
        ACC26(g12, w_reg[1], 4) ACC26(g13, w_reg[1], 5)
        ACC26(g14, w_reg[1], 6) ACC26(g15, w_reg[1], 7)
#undef ACC26
    }
    // pass 2, groups 2-7: R22 guarded single-group bodies.
#pragma unroll
    for (int k = 2; k < 8; ++k) {
        if (8 * k < c0) {
#pragma unroll
            for (int e = 0; e < 8; ++e) {
                int s = __builtin_amdgcn_readlane(sl, 8 * k + e);
                float wa = __shfl(w_reg[k], e * 8 + hA, 64);
                float wb = __shfl(w_reg[k], e * 8 + hA + 4, 64);
                float2 gf = __half22float2(h2p[(size_t)s * 64 + l]);
                accA = fmaf(wa, gf.x, accA);
                accB = fmaf(wb, gf.y, accB);
            }
        }
    }

    // deg>64 fallback (P~0 for Poisson(16)): R0's 2-hop loop, verbatim.
    for (int base = 64; base < deg; base += 64) {
        int rem = deg - base;
        if (rem > 64) rem = 64;
        int sl2 = (l < rem) ? csr[b + base + l] : 0;
        int g = 0;
        for (; g + 8 <= rem; g += 8) {
            int sg = __shfl(sl2, g + j8, 64);
            float w = __expf(lrelu(apf[sg * 8 + fidx] + dn));
            wsum += w;
#pragma unroll
            for (int j2 = 0; j2 < 8; ++j2) {
                int s = __builtin_amdgcn_readlane(sl2, g + j2);
                float wa = __shfl(w, j2 * 8 + hA, 64);
                float wb = __shfl(w, j2 * 8 + hA + 4, 64);
                float2 gg = __half22float2(h2p[(size_t)s * 64 + l]);
                accA = fmaf(wa, gg.x, accA);
                accB = fmaf(wb, gg.y, accB);
            }
        }
        if (g < rem) {
            int cnt2 = rem - g;
            int jj = (j8 < cnt2) ? j8 : 0;
            int sg = __shfl(sl2, g + jj, 64);
            float w = (j8 < cnt2) ? __expf(lrelu(apf[sg * 8 + fidx] + dn)) : 0.f;
            wsum += w;
            for (int j2 = 0; j2 < cnt2; ++j2) {
                int s = __builtin_amdgcn_readlane(sl2, g + j2);
                float wa = __shfl(w, j2 * 8 + hA, 64);
                float wb = __shfl(w, j2 * 8 + hA + 4, 64);
                float2 gg = __half22float2(h2p[(size_t)s * 64 + l]);
                accA = fmaf(wa, gg.x, accA);
                accB = fmaf(wb, gg.y, accB);
            }
        }
    }

    // edge-weight totals: after xor 8/16/32, lane m holds head m&7 total
    wsum += __shfl_xor(wsum, 8, 64);
    wsum += __shfl_xor(wsum, 16, 64);
    wsum += __shfl_xor(wsum, 32, 64);
    float denA = wA + __shfl(wsum, hA, 64);
    float denB = wB + __shfl(wsum, hA + 4, 64);

    // channel c=l&15: lanes {l, l^16, l^32, l^48} hold heads {0..3}x{+0,+4}
    float v = accA / denA + accB / denB;
    v += __shfl_xor(v, 16, 64);
    v += __shfl_xor(v, 32, 64);
    v *= 0.125f;
    if (l < 16) smv[wid][l] = v;
    if (l == 0) smg[wid] = batch[n];
    __syncthreads();
    if (t < 64) {
        int w = t >> 4, c = t & 15;
        int g = smg[w];
        bool leader = true;
        for (int w2 = 0; w2 < w; ++w2)
            if (smg[w2] == g) { leader = false; break; }
        if (leader) {
            float s = smv[w][c];
            for (int w2 = w + 1; w2 < 4; ++w2)
                if (smg[w2] == g) s += smv[w2][c];
            atomicAdd(&pool[g * 16 + c], s);
        }
    }
}

// ---- final: pooled mean (+b2) @ Wfc + bfc -> [64,4]
__global__ void k_final(const float* __restrict__ pool, const int* __restrict__ cnt,
                        const float* __restrict__ b2, const float* __restrict__ Wfc,
                        const float* __restrict__ bfc, float* __restrict__ out) {
    int t = threadIdx.x;
    int g = t >> 2, k = t & 3;
    float c = (float)(cnt[g] > 0 ? cnt[g] : 1);
    float acc = bfc[k];
#pragma unroll
    for (int ci = 0; ci < 16; ++ci)
        acc += (pool[g * 16 + ci] / c + b2[ci]) * Wfc[ci * 4 + k];
    out[g * 4 + k] = acc;
}

extern "C" void kernel_launch(void* const* d_in, const int* in_sizes, int n_in,
                              void* d_out, int out_size, void* d_ws, size_t ws_size,
                              hipStream_t stream) {
    const float* x   = (const float*)d_in[0];
    const float* W1  = (const float*)d_in[1];
    const float* as1 = (const float*)d_in[2];
    const float* ad1 = (const float*)d_in[3];
    const float* b1  = (const float*)d_in[4];
    const float* W2  = (const float*)d_in[5];
    const float* as2 = (const float*)d_in[6];
    const float* ad2 = (const float*)d_in[7];
    const float* b2  = (const float*)d_in[8];
    const float* Wfc = (const float*)d_in[9];
    const float* bfc = (const float*)d_in[10];
    const int* ei    = (const int*)d_in[11];
    const int* batch = (const int*)d_in[12];
    const int* srcv  = ei;             // edge_index[0]
    const int* dstv  = ei + N_EDGES;   // edge_index[1]

    char* ws = (char*)d_ws;
    size_t o = 0;
    auto alloc = [&](size_t bytes) {
        void* p = ws + o;
        o += (bytes + 255) & ~(size_t)255;
        return p;
    };
    // zero-region first (one memset): cnt, pool, gbin_cursor
    int*    cnt     = (int*)alloc(64 * 4);
    float*  pool    = (float*)alloc(64 * 16 * 4);
    int*    gbin    = (int*)alloc(NBIN * 4);
    size_t  zbytes  = o;
    int*    off     = (int*)alloc((size_t)(N_NODES + 1) * 4);
    int*    csr     = (int*)alloc((size_t)N_EDGES * 4);
    float2* ap      = (float2*)alloc((size_t)N_NODES * 4 * 8);
    float2* dp      = (float2*)alloc((size_t)N_NODES * 4 * 8);
    int*    binned  = (int*)alloc((size_t)NBIN * BINCAP * 4);    // 8.0 MB packed
    __half2* h2p    = (__half2*)alloc((size_t)N_NODES * 64 * 4); // 25.6 MB

    hipMemsetAsync(d_ws, 0, zbytes, stream);

    int nbA = (N_EDGES + EPB - 1) / EPB;   // 391

    k_binA<<<nbA, 1024, 0, stream>>>(srcv, dstv, batch, gbin, cnt, binned);
    k_megaB<<<NBIN, 1024, 0, stream>>>(binned, gbin, off, csr,
                                       x, W1, as1, ad1, b1, W2, as2, ad2,
                                       h2p, ap, dp);
    k_layer2<<<N_NODES / 4, 256, 0, stream>>>(h2p, ap, dp, off, csr, batch, pool);
    k_final<<<1, 256, 0, stream>>>(pool, cnt, b2, Wfc, bfc, (float*)d_out);
}

// Round 14
// 254.919 us; speedup vs baseline: 1.2223x; 1.1063x over previous
//
#include <hip/hip_runtime.h>
#include <hip/hip_fp16.h>

#define N_NODES  100000
#define N_EDGES  1600000
#define N_GRAPHS 64

#define BINSH  8
#define NBIN   392          // bins of 256 nodes (last ones empty-guarded)
#define BINCAP 5120         // Poisson(4081) max ~4.4K; safe headroom
#define EPB    4096         // edges per block in k_binA (1024 threads x 4)

typedef _Float16 half8 __attribute__((ext_vector_type(8)));
typedef float float4v __attribute__((ext_vector_type(4)));

__device__ __forceinline__ float lrelu(float v) { return v > 0.f ? v : 0.2f * v; }
__device__ __forceinline__ float elu_f(float v) { return v > 0.f ? v : __expf(v) - 1.f; }

// ---- Pass A: coarse-bin edges (dst>>8) into per-bin regions, coalesced runs.
// binned entries packed: (dst_local << 17) | src.
__global__ __launch_bounds__(1024) void k_binA(
    const int* __restrict__ src, const int* __restrict__ dst,
    const int* __restrict__ batch, int* __restrict__ gbin_cursor,
    int* __restrict__ cnt, int* __restrict__ binned) {
    __shared__ int hist[NBIN], lexcl[NBIN], runbase[NBIN], lcur[NBIN];
    __shared__ int wpart[16];
    __shared__ int gh[N_GRAPHS];
    __shared__ int2 stage[EPB];   // {packed, bin}  32 KB
    int t = threadIdx.x;
    int e0 = blockIdx.x * EPB;
    for (int b = t; b < NBIN; b += 1024) hist[b] = 0;
    if (t < N_GRAPHS) gh[t] = 0;
    __syncthreads();
    int nid = blockIdx.x * 1024 + t;   // 391*1024 >= N_NODES
    if (nid < N_NODES) atomicAdd(&gh[batch[nid]], 1);
    int e = 4 * t;
    int4 dv = make_int4(0, 0, 0, 0), sv = make_int4(0, 0, 0, 0);
    bool full = (e0 + e + 3 < N_EDGES);
    if (full) {
        dv = *(const int4*)(dst + e0 + e);
        sv = *(const int4*)(src + e0 + e);
        atomicAdd(&hist[dv.x >> BINSH], 1);
        atomicAdd(&hist[dv.y >> BINSH], 1);
        atomicAdd(&hist[dv.z >> BINSH], 1);
        atomicAdd(&hist[dv.w >> BINSH], 1);
    } else {
        for (int k = 0; k < 4; ++k)
            if (e0 + e + k < N_EDGES) atomicAdd(&hist[dst[e0 + e + k] >> BINSH], 1);
    }
    __syncthreads();
    int v = (t < NBIN) ? hist[t] : 0;
    int x = v;
#pragma unroll
    for (int d = 1; d < 64; d <<= 1) {
        int y = __shfl_up(x, d, 64);
        if ((t & 63) >= d) x += y;
    }
    if ((t & 63) == 63) wpart[t >> 6] = x;
    __syncthreads();
    if (t == 0) {
        int a = 0;
        for (int w = 0; w < 16; ++w) { int q = wpart[w]; wpart[w] = a; a += q; }
    }
    __syncthreads();
    int excl = x - v + wpart[t >> 6];
    if (t < NBIN) { lexcl[t] = excl; lcur[t] = excl; }
    __syncthreads();
    if (t < NBIN && v > 0) runbase[t] = atomicAdd(&gbin_cursor[t], v);
    if (t < N_GRAPHS && gh[t]) atomicAdd(&cnt[t], gh[t]);
    __syncthreads();
    if (full) {
        int p, b_;
        b_ = dv.x >> BINSH; p = atomicAdd(&lcur[b_], 1);
        stage[p] = make_int2(((dv.x & 255) << 17) | sv.x, b_);
        b_ = dv.y >> BINSH; p = atomicAdd(&lcur[b_], 1);
        stage[p] = make_int2(((dv.y & 255) << 17) | sv.y, b_);
        b_ = dv.z >> BINSH; p = atomicAdd(&lcur[b_], 1);
        stage[p] = make_int2(((dv.z & 255) << 17) | sv.z, b_);
        b_ = dv.w >> BINSH; p = atomicAdd(&lcur[b_], 1);
        stage[p] = make_int2(((dv.w & 255) << 17) | sv.w, b_);
    } else {
        for (int k = 0; k < 4; ++k) {
            if (e0 + e + k < N_EDGES) {
                int d = dst[e0 + e + k];
                int b_ = d >> BINSH;
                int p = atomicAdd(&lcur[b_], 1);
                stage[p] = make_int2(((d & 255) << 17) | src[e0 + e + k], b_);
            }
        }
    }
    __syncthreads();
    int m = N_EDGES - e0;
    if (m > EPB) m = EPB;
    for (int i = 4 * t; i < 4 * t + 4 && i < m; ++i) {
        int2 pr = stage[i];
        int b_ = pr.y;
        binned[(size_t)b_ * BINCAP + runbase[b_] + (i - lexcl[b_])] = pr.x;
    }
}

// ---- MEGA pass B (R15-proven, monolithic; R21 split regressed ~15us):
// counting sort -> off/csr, then IN-BLOCK: layer-1 (shuffle-reduce),
// exact-fp32 logits, MFMA h2 GEMM.
__global__ __launch_bounds__(1024) void k_megaB(
    const int* __restrict__ binned, const int* __restrict__ gbin_cursor,
    int* __restrict__ off, int* __restrict__ csr,
    const float* __restrict__ x, const float* __restrict__ W1,
    const float* __restrict__ as1, const float* __restrict__ ad1,
    const float* __restrict__ b1, const float* __restrict__ W2,
    const float* __restrict__ as2, const float* __restrict__ ad2,
    __half2* __restrict__ h2p, float2* __restrict__ ap, float2* __restrict__ dp) {
    __shared__ int hist[256], lstart[256];
    __shared__ int wpart[4];
    __shared__ int s_ebase;
    __shared__ float s1l[256 * 8];
    __shared__ float smWs[512], smWd[512];
    __shared__ float smW1[64], smB1[64];
    __shared__ float ws8s[8], wd8s[8];
    __shared__ _Float16 smWT[128 * 72];
    __shared__ _Float16 smA[256 * 72];
    int b = blockIdx.x, t = threadIdx.x;
    int count = gbin_cursor[b];
    int node0 = b << BINSH;
    const int* my = binned + (size_t)b * BINCAP;

    if (t == 0) s_ebase = 0;
    if (t < 256) hist[t] = 0;
    for (int idx = t; idx < 8192; idx += 1024) {
        int c = idx >> 6, k = idx & 63;
        smWT[c * 72 + k] = (_Float16)W2[k * 128 + c];
    }
    {
        int tt = t & 511;
        int k = tt >> 3, h = tt & 7;
        const float* att = (t < 512) ? as2 : ad2;
        float acc = 0.f;
        for (int c = 0; c < 16; ++c)
            acc += W2[k * 128 + h * 16 + c] * att[h * 16 + c];
        if (t < 512) smWs[k * 8 + h] = acc; else smWd[k * 8 + h] = acc;
    }
    if (t < 64) { smW1[t] = W1[t]; smB1[t] = b1[t]; }
    if (t >= 64 && t < 72) {
        int h = t - 64;
        float s = 0.f, d = 0.f;
        for (int c = 0; c < 8; ++c) {
            float w = W1[h * 8 + c];
            s += w * as1[h * 8 + c];
            d += w * ad1[h * 8 + c];
        }
        ws8s[h] = s;
        wd8s[h] = d;
    }
    __syncthreads();

    if (t < b) atomicAdd(&s_ebase, gbin_cursor[t]);
    for (int i = t; i < count; i += 1024) atomicAdd(&hist[my[i] >> 17], 1);
    __syncthreads();

    int v = (t < 256) ? hist[t] : 0;
    int xx = v;
#pragma unroll
    for (int d = 1; d < 64; d <<= 1) {
        int y = __shfl_up(xx, d, 64);
        if ((t & 63) >= d) xx += y;
    }
    if (t < 256 && (t & 63) == 63) wpart[t >> 6] = xx;
    __syncthreads();
    if (t == 0) {
        int a = 0;
        for (int w = 0; w < 4; ++w) { int q = wpart[w]; wpart[w] = a; a += q; }
    }
    __syncthreads();
    int ebase = s_ebase;
    int excl = xx - v + ((t < 256) ? wpart[t >> 6] : 0);
    if (t < 256) {
        int n = node0 + t;
        if (n < N_NODES) off[n] = ebase + excl;
        lstart[t] = excl;
        hist[t] = excl;    // cursor
    }
    if (b == 0 && t == 0) off[N_NODES] = N_EDGES;
    __syncthreads();

    for (int i = t; i < count; i += 1024) {
        int pr = my[i];
        int p = atomicAdd(&hist[pr >> 17], 1);
        csr[ebase + p] = pr & 0x1FFFF;
    }
    __syncthreads();

    // layer 1: 4 lanes/node shuffle-reduce
    {
        int nl = t >> 2, c = t & 3;
        int n = node0 + nl;
        float ws[8], wd[8];
#pragma unroll
        for (int h = 0; h < 8; ++h) { ws[h] = ws8s[h]; wd[h] = wd8s[h]; }
        float xn = (n < N_NODES) ? x[n] : 0.f;
        float num[8], den[8];
#pragma unroll
        for (int h = 0; h < 8; ++h) { num[h] = 0.f; den[h] = 0.f; }
        if (c == 0 && n < N_NODES) {
#pragma unroll
            for (int h = 0; h < 8; ++h) {
                float w = __expf(lrelu(xn * ws[h] + xn * wd[h]));
                den[h] = w;
                num[h] = w * xn;
            }
        }
        int st = lstart[nl], en = hist[nl];
        for (int j = st + c; j < en; j += 4) {
            int s = csr[ebase + j];
            float xs = x[s];
#pragma unroll
            for (int h = 0; h < 8; ++h) {
                float w = __expf(lrelu(xs * ws[h] + xn * wd[h]));
                den[h] += w;
                num[h] += w * xs;
            }
        }
#pragma unroll
        for (int d = 1; d < 4; d <<= 1) {
#pragma unroll
            for (int h = 0; h < 8; ++h) {
                num[h] += __shfl_xor(num[h], d, 64);
                den[h] += __shfl_xor(den[h], d, 64);
            }
        }
        if (c == 0) {
#pragma unroll
            for (int h = 0; h < 8; ++h)
                s1l[nl * 8 + h] = (n < N_NODES) ? num[h] / den[h] : 0.f;
        }
    }
    __syncthreads();

    // exact-fp32 logits + smA fill
    {
        int nl = t >> 2, j = t & 3;
        int n = node0 + nl;
        if (n < N_NODES) {
            float pSA = 0.f, pSB = 0.f, pDA = 0.f, pDB = 0.f;
#pragma unroll 8
            for (int k = 0; k < 64; ++k) {
                float h1a = elu_f(s1l[nl * 8 + (k >> 3)] * smW1[k] + smB1[k]);
                pSA += h1a * smWs[k * 8 + j];
                pSB += h1a * smWs[k * 8 + j + 4];
                pDA += h1a * smWd[k * 8 + j];
                pDB += h1a * smWd[k * 8 + j + 4];
            }
            ap[n * 4 + j] = make_float2(pSA, pSB);
            dp[n * 4 + j] = make_float2(pDA, pDB);
        }
    }
    for (int i = t; i < 256 * 64; i += 1024) {
        int m = i >> 6, k = i & 63;
        smA[m * 72 + k] = (_Float16)elu_f(s1l[m * 8 + (k >> 3)] * smW1[k] + smB1[k]);
    }
    __syncthreads();

    // MFMA h2 GEMM, 16 waves x 16 nodes
    {
        int wave = t >> 6, lane = t & 63;
        int quad = lane >> 4, m15 = lane & 15;
        half8 a0 = *reinterpret_cast<const half8*>(&smA[(wave * 16 + m15) * 72 + quad * 8]);
        half8 a1 = *reinterpret_cast<const half8*>(&smA[(wave * 16 + m15) * 72 + 32 + quad * 8]);
        float4v acc[8];
#pragma unroll
        for (int tl = 0; tl < 8; ++tl) {
            half8 b0 = *reinterpret_cast<const half8*>(&smWT[(tl * 16 + m15) * 72 + quad * 8]);
            half8 b1v = *reinterpret_cast<const half8*>(&smWT[(tl * 16 + m15) * 72 + 32 + quad * 8]);
            float4v c = {0.f, 0.f, 0.f, 0.f};
            c = __builtin_amdgcn_mfma_f32_16x16x32_f16(a0, b0, c, 0, 0, 0);
            c = __builtin_amdgcn_mfma_f32_16x16x32_f16(a1, b1v, c, 0, 0, 0);
            acc[tl] = c;
        }
#pragma unroll
        for (int tl = 0; tl < 4; ++tl) {
#pragma unroll
            for (int reg = 0; reg < 4; ++reg) {
                int n = node0 + wave * 16 + quad * 4 + reg;
                if (n < N_NODES)
                    h2p[n * 64 + tl * 16 + m15] =
                        __floats2half2_rn(acc[tl][reg], acc[tl + 4][reg]);
            }
        }
    }
}

// ---- Layer 2 aggregation: R22 FINAL (verified best, 98us / 256us total).
// Two-phase without intra-group guards: pad sl with SELF node (valid
// address), mask invalid weights via select, guard only whole 8-edge
// groups (wave-uniform). This recovered load batching that R20's per-edge
// guards fenced (151us). Deeper staging was tried and is a dead end at
// HIP source level: R23 (guarded gbuf[16]) null; R24 (paired gbuf) and
// R25 (top-level gbuf) spilled the aggregate to scratch (WRITE_SIZE
// 51/277 MB); R26 (16 named scalars) STILL spilled (151 MB) -- the
// allocator pegs this kernel at 32 VGPR and will not widen past ~8
// in-flight gathers. 98us @ VALUBusy 48% / HBM 35% / 0 bank conflicts is
// the latency floor of this structure. NO device-scope fence (R16).
__global__ __launch_bounds__(256, 8) void k_layer2(
    const __half2* __restrict__ h2p, const float2* __restrict__ ap,
    const float2* __restrict__ dp, const int* __restrict__ off,
    const int* __restrict__ csr, const int* __restrict__ batch,
    float* __restrict__ pool) {
    __shared__ float smv[4][16];
    __shared__ int smg[4];
    const float* apf = (const float*)ap;   // flat: node*8 + 2*(h&3) + (h>>2)
    const float* dpf = (const float*)dp;
    int t = threadIdx.x;
    int wid = t >> 6, l = t & 63;
    int n = blockIdx.x * 4 + wid;  // grid exact: 25000*4 == N_NODES
    int hA = l >> 4;               // head of x component; y component = hA+4
    int hh = l & 7;
    int j8 = l >> 3;
    int fidx = 2 * (hh & 3) + (hh >> 2);
    float dn = dpf[n * 8 + fidx];

    // self-loop seed
    float2 ad = dp[n * 4 + hA];
    float2 an = ap[n * 4 + hA];
    float wA = __expf(lrelu(an.x + ad.x));
    float wB = __expf(lrelu(an.y + ad.y));
    float2 hn = __half22float2(h2p[(size_t)n * 64 + l]);
    float accA = wA * hn.x, accB = wB * hn.y;
    float wsum = 0.f;

    int b = off[n];
    int deg = off[n + 1] - b;
    int c0 = deg < 64 ? deg : 64;
    int sl = (l < c0) ? csr[b + l] : n;   // pad with self (valid address)

    // pass 1: edge weights into w_reg, independent gathers batched.
    float w_reg[8];
#pragma unroll
    for (int k = 0; k < 8; ++k) w_reg[k] = 0.f;
#pragma unroll
    for (int k = 0; k < 8; ++k) {
        if (8 * k < c0) {                 // wave-uniform group guard only
            int sg = __shfl(sl, 8 * k + j8, 64);
            float w = __expf(lrelu(apf[sg * 8 + fidx] + dn));
            w = (8 * k + j8 < c0) ? w : 0.f;   // select, not branch
            w_reg[k] = w;
            wsum += w;
        }
    }

    // pass 2: branch-free 8-edge bodies; tail edges have w==0 and gather
    // the (L2-hot) self row harmlessly.
#pragma unroll
    for (int k = 0; k < 8; ++k) {
        if (8 * k < c0) {
#pragma unroll
            for (int e = 0; e < 8; ++e) {
                int s = __builtin_amdgcn_readlane(sl, 8 * k + e);
                float wa = __shfl(w_reg[k], e * 8 + hA, 64);
                float wb = __shfl(w_reg[k], e * 8 + hA + 4, 64);
                float2 gf = __half22float2(h2p[(size_t)s * 64 + l]);
                accA = fmaf(wa, gf.x, accA);
                accB = fmaf(wb, gf.y, accB);
            }
        }
    }

    // deg>64 fallback (P~0 for Poisson(16)): R0's 2-hop loop, verbatim.
    for (int base = 64; base < deg; base += 64) {
        int rem = deg - base;
        if (rem > 64) rem = 64;
        int sl2 = (l < rem) ? csr[b + base + l] : 0;
        int g = 0;
        for (; g + 8 <= rem; g += 8) {
            int sg = __shfl(sl2, g + j8, 64);
            float w = __expf(lrelu(apf[sg * 8 + fidx] + dn));
            wsum += w;
#pragma unroll
            for (int j2 = 0; j2 < 8; ++j2) {
                int s = __builtin_amdgcn_readlane(sl2, g + j2);
                float wa = __shfl(w, j2 * 8 + hA, 64);
                float wb = __shfl(w, j2 * 8 + hA + 4, 64);
                float2 gg = __half22float2(h2p[(size_t)s * 64 + l]);
                accA = fmaf(wa, gg.x, accA);
                accB = fmaf(wb, gg.y, accB);
            }
        }
        if (g < rem) {
            int cnt2 = rem - g;
            int jj = (j8 < cnt2) ? j8 : 0;
            int sg = __shfl(sl2, g + jj, 64);
            float w = (j8 < cnt2) ? __expf(lrelu(apf[sg * 8 + fidx] + dn)) : 0.f;
            wsum += w;
            for (int j2 = 0; j2 < cnt2; ++j2) {
                int s = __builtin_amdgcn_readlane(sl2, g + j2);
                float wa = __shfl(w, j2 * 8 + hA, 64);
                float wb = __shfl(w, j2 * 8 + hA + 4, 64);
                float2 gg = __half22float2(h2p[(size_t)s * 64 + l]);
                accA = fmaf(wa, gg.x, accA);
                accB = fmaf(wb, gg.y, accB);
            }
        }
    }

    // edge-weight totals: after xor 8/16/32, lane m holds head m&7 total
    wsum += __shfl_xor(wsum, 8, 64);
    wsum += __shfl_xor(wsum, 16, 64);
    wsum += __shfl_xor(wsum, 32, 64);
    float denA = wA + __shfl(wsum, hA, 64);
    float denB = wB + __shfl(wsum, hA + 4, 64);

    // channel c=l&15: lanes {l, l^16, l^32, l^48} hold heads {0..3}x{+0,+4}
    float v = accA / denA + accB / denB;
    v += __shfl_xor(v, 16, 64);
    v += __shfl_xor(v, 32, 64);
    v *= 0.125f;
    if (l < 16) smv[wid][l] = v;
    if (l == 0) smg[wid] = batch[n];
    __syncthreads();
    if (t < 64) {
        int w = t >> 4, c = t & 15;
        int g = smg[w];
        bool leader = true;
        for (int w2 = 0; w2 < w; ++w2)
            if (smg[w2] == g) { leader = false; break; }
        if (leader) {
            float s = smv[w][c];
            for (int w2 = w + 1; w2 < 4; ++w2)
                if (smg[w2] == g) s += smv[w2][c];
            atomicAdd(&pool[g * 16 + c], s);
        }
    }
}

// ---- final: pooled mean (+b2) @ Wfc + bfc -> [64,4]
__global__ void k_final(const float* __restrict__ pool, const int* __restrict__ cnt,
                        const float* __restrict__ b2, const float* __restrict__ Wfc,
                        const float* __restrict__ bfc, float* __restrict__ out) {
    int t = threadIdx.x;
    int g = t >> 2, k = t & 3;
    float c = (float)(cnt[g] > 0 ? cnt[g] : 1);
    float acc = bfc[k];
#pragma unroll
    for (int ci = 0; ci < 16; ++ci)
        acc += (pool[g * 16 + ci] / c + b2[ci]) * Wfc[ci * 4 + k];
    out[g * 4 + k] = acc;
}

extern "C" void kernel_launch(void* const* d_in, const int* in_sizes, int n_in,
                              void* d_out, int out_size, void* d_ws, size_t ws_size,
                              hipStream_t stream) {
    const float* x   = (const float*)d_in[0];
    const float* W1  = (const float*)d_in[1];
    const float* as1 = (const float*)d_in[2];
    const float* ad1 = (const float*)d_in[3];
    const float* b1  = (const float*)d_in[4];
    const float* W2  = (const float*)d_in[5];
    const float* as2 = (const float*)d_in[6];
    const float* ad2 = (const float*)d_in[7];
    const float* b2  = (const float*)d_in[8];
    const float* Wfc = (const float*)d_in[9];
    const float* bfc = (const float*)d_in[10];
    const int* ei    = (const int*)d_in[11];
    const int* batch = (const int*)d_in[12];
    const int* srcv  = ei;             // edge_index[0]
    const int* dstv  = ei + N_EDGES;   // edge_index[1]

    char* ws = (char*)d_ws;
    size_t o = 0;
    auto alloc = [&](size_t bytes) {
        void* p = ws + o;
        o += (bytes + 255) & ~(size_t)255;
        return p;
    };
    // zero-region first (one memset): cnt, pool, gbin_cursor
    int*    cnt     = (int*)alloc(64 * 4);
    float*  pool    = (float*)alloc(64 * 16 * 4);
    int*    gbin    = (int*)alloc(NBIN * 4);
    size_t  zbytes  = o;
    int*    off     = (int*)alloc((size_t)(N_NODES + 1) * 4);
    int*    csr     = (int*)alloc((size_t)N_EDGES * 4);
    float2* ap      = (float2*)alloc((size_t)N_NODES * 4 * 8);
    float2* dp      = (float2*)alloc((size_t)N_NODES * 4 * 8);
    int*    binned  = (int*)alloc((size_t)NBIN * BINCAP * 4);    // 8.0 MB packed
    __half2* h2p    = (__half2*)alloc((size_t)N_NODES * 64 * 4); // 25.6 MB

    hipMemsetAsync(d_ws, 0, zbytes, stream);

    int nbA = (N_EDGES + EPB - 1) / EPB;   // 391

    k_binA<<<nbA, 1024, 0, stream>>>(srcv, dstv, batch, gbin, cnt, binned);
    k_megaB<<<NBIN, 1024, 0, stream>>>(binned, gbin, off, csr,
                                       x, W1, as1, ad1, b1, W2, as2, ad2,
                                       h2p, ap, dp);
    k_layer2<<<N_NODES / 4, 256, 0, stream>>>(h2p, ap, dp, off, csr, batch, pool);
    k_final<<<1, 256, 0, stream>>>(pool, cnt, b2, Wfc, bfc, (float*)d_out);
}